// Round 4
// baseline (336.507 us; speedup 1.0000x reference)
//
#include <hip/hip_runtime.h>
#include <hip/hip_cooperative_groups.h>
#include <cmath>

namespace cg = cooperative_groups;

constexpr int NBLK = 256;   // == CU count: cooperative launch always fits at 1 block/CU
constexpr int NTHR = 512;   // two virtual 256-thread half-blocks per block

struct KArgs {
    const float* feat; const float* mask; const float* agg_w; const float* agg_b;
    const float* upd_w; const float* upd_b; const float* attn_w;
    float* out;
    float* wt12;   // [256][512]: cols [0,256)=W1^T, [256,512)=M1^T (M1=agg_w@U1)
    float* u1t;    // [256][256]: U1^T
    float* awt;    // [256][256]: agg_w^T
    float* u2t;    // [256][256]: U2^T
    float* buf0;   // [2048][256]
    float* buf1;   // [2048][256]
    float* pz;     // [512][256] softmax partial sums (per 4-row group)
    float* pa;     // [512][256] softmax partial weighted sums
    float* cAv;    // [16][256]
};

// ---------------- shared device helpers (cooperative path) ----------------

// 32x32-tile transpose: dst[k][e] = src[e*sld + scol0 + k]
__device__ inline void transp(const float* __restrict__ src, int sld, int scol0,
                              float* __restrict__ dst, int dld,
                              int ti, int tt, float* lds /*>=32*33*/) {
    const int tr = (ti >> 3) * 32;
    const int tc = (ti & 7) * 32;
    const int rr = tt >> 5;
    const int cc = tt & 31;
    #pragma unroll
    for (int p = 0; p < 4; ++p) {
        int row = p * 8 + rr;
        lds[row * 33 + cc] = src[(size_t)(tr + row) * sld + scol0 + tc + cc];
    }
    __syncthreads();
    #pragma unroll
    for (int p = 0; p < 4; ++p) {
        int krow = p * 8 + rr;
        dst[(size_t)(tc + krow) * dld + tr + cc] = lds[cc * 33 + krow];
    }
    __syncthreads();
}

// stage 16x256 A-tile into LDS. AMODE 0: plain; 1: *mask[r]; 2: m*(src+cadd)+aggb
template<int AMODE>
__device__ inline void stageA(const float* __restrict__ src, const float* __restrict__ maskp,
                              const float* __restrict__ aggb, const float* __restrict__ cadd,
                              int r0, int tt, float (&As)[16][264]) {
    const int row = tt >> 4, k4 = (tt & 15) * 16;
    const float* sp = src + (size_t)(r0 + row) * 256 + k4;
    float mv = (AMODE != 0) ? maskp[r0 + row] : 1.f;
    #pragma unroll
    for (int j = 0; j < 4; ++j) {
        float4 v = *(const float4*)(sp + 4 * j);
        if (AMODE == 1) { v.x *= mv; v.y *= mv; v.z *= mv; v.w *= mv; }
        else if (AMODE == 2) {
            float4 c4 = *(const float4*)(cadd + k4 + 4 * j);
            float4 b4 = *(const float4*)(aggb + k4 + 4 * j);
            v.x = fmaf(mv, v.x + c4.x, b4.x);
            v.y = fmaf(mv, v.y + c4.y, b4.y);
            v.z = fmaf(mv, v.z + c4.z, b4.z);
            v.w = fmaf(mv, v.w + c4.w, b4.w);
        }
        *(float4*)&As[row][k4 + 4 * j] = v;
    }
}

template<int WLD>
__device__ inline void gcore(const float (&As)[16][264], const float* __restrict__ Wt,
                             int c0, int lane, int rw, float (&acc)[4][2]) {
    const float* wp = Wt + c0 + 2 * lane;
    #pragma unroll 4
    for (int kq = 0; kq < 64; ++kq) {
        float2 w0 = *(const float2*)(wp);
        float2 w1 = *(const float2*)(wp + WLD);
        float2 w2 = *(const float2*)(wp + 2 * WLD);
        float2 w3 = *(const float2*)(wp + 3 * WLD);
        wp += 4 * WLD;
        const int k = kq * 4;
        float4 a0 = *(const float4*)&As[rw + 0][k];
        float4 a1 = *(const float4*)&As[rw + 1][k];
        float4 a2 = *(const float4*)&As[rw + 2][k];
        float4 a3 = *(const float4*)&As[rw + 3][k];
#define RS(r, ar)                                         \
        acc[r][0] = fmaf(ar.x, w0.x, acc[r][0]);          \
        acc[r][0] = fmaf(ar.y, w1.x, acc[r][0]);          \
        acc[r][0] = fmaf(ar.z, w2.x, acc[r][0]);          \
        acc[r][0] = fmaf(ar.w, w3.x, acc[r][0]);          \
        acc[r][1] = fmaf(ar.x, w0.y, acc[r][1]);          \
        acc[r][1] = fmaf(ar.y, w1.y, acc[r][1]);          \
        acc[r][1] = fmaf(ar.z, w2.y, acc[r][1]);          \
        acc[r][1] = fmaf(ar.w, w3.y, acc[r][1]);
        RS(0, a0) RS(1, a1) RS(2, a2) RS(3, a3)
#undef RS
    }
}

template<int AMODE, bool USE_U1>
__device__ inline void big_step(const KArgs& A, const float* __restrict__ Asrc,
                                float* __restrict__ g2dst,
                                int vb, int tt, int lane, int wv, int rw,
                                float (&As)[16][264], float (&acc)[4][2]) {
    const int bx = vb >> 2, by = vb & 3;
    const int r0 = bx * 16;
    const int b  = bx >> 3;
    stageA<AMODE>(Asrc, A.mask, A.agg_b, A.cAv + b * 256, r0, tt, As);
    __syncthreads();
    #pragma unroll
    for (int r = 0; r < 4; ++r) { acc[r][0] = 0.f; acc[r][1] = 0.f; }
    if (by < 2) {
        gcore<512>(As, A.wt12, by * 128, lane, rw, acc);
        const int gg = bx * 4 + wv;
        const int e = by * 128 + 2 * lane;
        float pzv[2], pav[2];
        #pragma unroll
        for (int c = 0; c < 2; ++c) {
            float p0 = __expf(acc[0][c]);
            float p1 = __expf(acc[1][c]);
            float p2 = __expf(acc[2][c]);
            float p3 = __expf(acc[3][c]);
            const int ee = e + c;
            pav[c] = p0 * As[rw + 0][ee] + p1 * As[rw + 1][ee]
                   + p2 * As[rw + 2][ee] + p3 * As[rw + 3][ee];
            pzv[c] = (p0 + p1) + (p2 + p3);
        }
        *(float2*)(A.pz + (size_t)gg * 256 + e) = make_float2(pzv[0], pzv[1]);
        *(float2*)(A.pa + (size_t)gg * 256 + e) = make_float2(pav[0], pav[1]);
    } else {
        if (!USE_U1) gcore<512>(As, A.wt12 + 256, (by - 2) * 128, lane, rw, acc);
        else         gcore<256>(As, A.u1t,        (by - 2) * 128, lane, rw, acc);
        if (g2dst) {
            const int e = (by - 2) * 128 + 2 * lane;
            #pragma unroll
            for (int r = 0; r < 4; ++r)
                *(float2*)(g2dst + (size_t)(r0 + rw + r) * 256 + e) =
                    make_float2(acc[r][0], acc[r][1]);
        }
    }
}

__device__ inline void ck_phase(const KArgs& A, int vb, int tt,
                                float* aggs, float* csv) {
    if (vb >= 16) return;
    const int b = vb;
    float z = 0.f, a = 0.f;
    #pragma unroll 8
    for (int g = 0; g < 32; ++g) {
        size_t idx = (size_t)(b * 32 + g) * 256 + tt;
        z += A.pz[idx]; a += A.pa[idx];
    }
    aggs[tt] = 1.f / (1.f + __expf(-(a / z)));
    __syncthreads();
    float c = A.upd_b[tt];
    #pragma unroll 8
    for (int d = 0; d < 256; ++d)
        c = fmaf(aggs[d], A.u2t[d * 256 + tt], c);
    csv[tt] = c;
    __syncthreads();
    float ca = 0.f;
    #pragma unroll 8
    for (int d = 0; d < 256; ++d)
        ca = fmaf(csv[d], A.awt[d * 256 + tt], ca);
    A.cAv[b * 256 + tt] = ca;
}

__global__ __launch_bounds__(NTHR, 2) void mega(KArgs A) {
    cg::grid_group grid = cg::this_grid();
    const int t  = threadIdx.x;
    const int ht = t >> 8;              // virtual half-block id within block
    const int tt = t & 255;
    const int vb = blockIdx.x * 2 + ht; // virtual block id, 0..511
    const int lane = t & 63, wv = (t >> 6) & 3, rw = wv * 4;

    __shared__ __align__(16) float AsBuf[2][16][264];
    __shared__ __align__(16) float aggsB[2][256];
    __shared__ __align__(16) float csvB[2][256];
    float (&As)[16][264] = AsBuf[ht];
    float* aggs = aggsB[ht];
    float* csv  = csvB[ht];

    // ---- P0: weight prep ----
    if (vb < 256) {
        // M1[e=vb][f=tt] = sum_d agg_w[e][d]*upd_w[d*512+f] -> wt12[f][256+e]
        aggs[tt] = A.agg_w[(size_t)vb * 256 + tt];
        __syncthreads();
        float acc = 0.f;
        #pragma unroll 8
        for (int d = 0; d < 256; ++d)
            acc = fmaf(aggs[d], A.upd_w[(size_t)d * 512 + tt], acc);
        A.wt12[(size_t)tt * 512 + 256 + vb] = acc;
    } else {
        const int ti = (vb - 256) & 63;
        const int which = (vb - 256) >> 6;
        float* lds = &As[0][0];
        if (which == 0)      transp(A.attn_w, 512, 0,   A.wt12, 512, ti, tt, lds);
        else if (which == 1) transp(A.upd_w,  512, 0,   A.u1t,  256, ti, tt, lds);
        else if (which == 2) transp(A.agg_w,  256, 0,   A.awt,  256, ti, tt, lds);
        else                 transp(A.upd_w,  512, 256, A.u2t,  256, ti, tt, lds);
    }
    grid.sync();   // 1

    // ---- P1: G0: xhid_1 = (feat*mask) @ agg_w^T + agg_b -> buf0 ----
    if (vb < 256) {
        const int bx = vb >> 1, by = vb & 1;
        const int r0 = bx * 16;
        stageA<1>(A.feat, A.mask, nullptr, nullptr, r0, tt, As);
        __syncthreads();
        float acc0[4][2] = {};
        gcore<256>(As, A.awt, by * 128, lane, rw, acc0);
        const int e = by * 128 + 2 * lane;
        float2 bias = *(const float2*)(A.agg_b + e);
        #pragma unroll
        for (int r = 0; r < 4; ++r)
            *(float2*)(A.buf0 + (size_t)(r0 + rw + r) * 256 + e) =
                make_float2(acc0[r][0] + bias.x, acc0[r][1] + bias.y);
    }
    grid.sync();   // 2

    float acc[4][2];

    // ---- step 1 ----
    big_step<0, false>(A, A.buf0, A.buf1, vb, tt, lane, wv, rw, As, acc);
    grid.sync();   // 3
    ck_phase(A, vb, tt, aggs, csv);
    grid.sync();   // 4

    // ---- step 2 ----
    big_step<2, false>(A, A.buf1, A.buf0, vb, tt, lane, wv, rw, As, acc);
    grid.sync();   // 5
    ck_phase(A, vb, tt, aggs, csv);
    grid.sync();   // 6

    // ---- step 3 (G2_3 kept in registers) ----
    big_step<2, true>(A, A.buf0, nullptr, vb, tt, lane, wv, rw, As, acc);
    grid.sync();   // 7

    // ---- final: by>=2 halves compute c3 for own e-slice, add, store ----
    {
        const int bx = vb >> 2, by = vb & 3;
        if (by >= 2) {
            const int b = bx >> 3;
            float z = 0.f, a = 0.f;
            #pragma unroll 8
            for (int g = 0; g < 32; ++g) {
                size_t idx = (size_t)(b * 32 + g) * 256 + tt;
                z += A.pz[idx]; a += A.pa[idx];
            }
            aggs[tt] = 1.f / (1.f + __expf(-(a / z)));
            __syncthreads();
            const int e = (by - 2) * 128 + 2 * lane;
            float c0v = A.upd_b[e], c1v = A.upd_b[e + 1];
            #pragma unroll 8
            for (int d = 0; d < 256; ++d) {
                float ag = aggs[d];
                float2 u2 = *(const float2*)(A.u2t + d * 256 + e);
                c0v = fmaf(ag, u2.x, c0v);
                c1v = fmaf(ag, u2.y, c1v);
            }
            const int r0 = bx * 16;
            #pragma unroll
            for (int r = 0; r < 4; ++r)
                *(float2*)(A.out + (size_t)(r0 + rw + r) * 256 + e) =
                    make_float2(acc[r][0] + c0v, acc[r][1] + c1v);
        }
    }
}

// ======================= fallback path (proven R2 code) =======================

__global__ __launch_bounds__(256) void fb_prep(
    const float* __restrict__ agg_w, const float* __restrict__ attn_w,
    const float* __restrict__ upd_w,
    float* __restrict__ wt12, float* __restrict__ wt3,
    float* __restrict__ awt,  float* __restrict__ u2t)
{
    const int bx = blockIdx.x, t = threadIdx.x;
    if (bx < 64) {
        __shared__ float agL[4][256];
        const int e0 = bx * 4;
        {
            int row = t >> 6, d0 = (t & 63) * 4;
            *(float4*)&agL[row][d0] = *(const float4*)(agg_w + (e0 + row) * 256 + d0);
        }
        __syncthreads();
        float acc[4] = {0.f, 0.f, 0.f, 0.f};
        #pragma unroll 4
        for (int d = 0; d < 256; ++d) {
            float u = upd_w[d * 512 + t];
            acc[0] = fmaf(agL[0][d], u, acc[0]);
            acc[1] = fmaf(agL[1][d], u, acc[1]);
            acc[2] = fmaf(agL[2][d], u, acc[2]);
            acc[3] = fmaf(agL[3][d], u, acc[3]);
        }
        #pragma unroll
        for (int i = 0; i < 4; ++i)
            wt12[t * 512 + 256 + e0 + i] = acc[i];
    } else {
        const int kg = bx - 64;
        #pragma unroll 2
        for (int j = 0; j < 16; ++j) {
            int k = kg * 16 + j;
            wt12[k * 512 + t]       = attn_w[t * 512 + k];
            wt3 [k * 512 + t]       = attn_w[t * 512 + k];
            wt3 [k * 512 + 256 + t] = upd_w[t * 512 + k];
            awt [k * 256 + t]       = agg_w[t * 256 + k];
            u2t [k * 256 + t]       = upd_w[t * 512 + 256 + k];
        }
    }
}

template<int AMODE, int EPI>
__global__ __launch_bounds__(256) void fb_gemm(
    const float* __restrict__ Asrc, const float* __restrict__ Wt, int wld,
    const float* __restrict__ maskp, const float* __restrict__ cA,
    const float* __restrict__ aggb,
    float* __restrict__ gout,
    float* __restrict__ pm, float* __restrict__ pz, float* __restrict__ pa)
{
    __shared__ float As[16][264];
    const int t    = threadIdx.x;
    const int lane = t & 63, wv = t >> 6;
    const int bx = blockIdx.x, by = blockIdx.y;
    const int r0 = bx * 16;
    const int c0 = by * 128;
    const int b  = r0 >> 7;

    {
        int row = t >> 4;
        int k4  = (t & 15) * 16;
        const float* src = Asrc + (size_t)(r0 + row) * 256 + k4;
        float mv = (AMODE != 0) ? maskp[r0 + row] : 1.f;
        #pragma unroll
        for (int j = 0; j < 4; ++j) {
            float4 v = *(const float4*)(src + 4 * j);
            if (AMODE == 1) { v.x *= mv; v.y *= mv; v.z *= mv; v.w *= mv; }
            if (AMODE == 2) {
                float4 c4 = *(const float4*)(cA + b * 256 + k4 + 4 * j);
                float4 a4 = *(const float4*)(aggb + k4 + 4 * j);
                v.x = fmaf(mv, v.x + c4.x, a4.x);
                v.y = fmaf(mv, v.y + c4.y, a4.y);
                v.z = fmaf(mv, v.z + c4.z, a4.z);
                v.w = fmaf(mv, v.w + c4.w, a4.w);
            }
            *(float4*)&As[row][k4 + 4 * j] = v;
        }
    }
    __syncthreads();

    float acc[4][2] = {};
    const float* wp = Wt + c0 + 2 * lane;
    const int rw = wv * 4;
    #pragma unroll 4
    for (int kq = 0; kq < 64; ++kq) {
        float2 w0 = *(const float2*)(wp);
        float2 w1 = *(const float2*)(wp + wld);
        float2 w2 = *(const float2*)(wp + 2 * wld);
        float2 w3 = *(const float2*)(wp + 3 * wld);
        wp += 4 * wld;
        const int k = kq * 4;
        float4 a0 = *(const float4*)&As[rw + 0][k];
        float4 a1 = *(const float4*)&As[rw + 1][k];
        float4 a2 = *(const float4*)&As[rw + 2][k];
        float4 a3 = *(const float4*)&As[rw + 3][k];
#define RS(r, ar)                                         \
        acc[r][0] = fmaf(ar.x, w0.x, acc[r][0]);          \
        acc[r][0] = fmaf(ar.y, w1.x, acc[r][0]);          \
        acc[r][0] = fmaf(ar.z, w2.x, acc[r][0]);          \
        acc[r][0] = fmaf(ar.w, w3.x, acc[r][0]);          \
        acc[r][1] = fmaf(ar.x, w0.y, acc[r][1]);          \
        acc[r][1] = fmaf(ar.y, w1.y, acc[r][1]);          \
        acc[r][1] = fmaf(ar.z, w2.y, acc[r][1]);          \
        acc[r][1] = fmaf(ar.w, w3.y, acc[r][1]);
        RS(0, a0) RS(1, a1) RS(2, a2) RS(3, a3)
#undef RS
    }

    if (EPI == 0) {
        const int e = c0 + 2 * lane;
        float2 bias = *(const float2*)(aggb + e);
        #pragma unroll
        for (int r = 0; r < 4; ++r)
            *(float2*)(gout + (size_t)(r0 + rw + r) * 256 + e) =
                make_float2(acc[r][0] + bias.x, acc[r][1] + bias.y);
    } else {
        if (by < 2) {
            const int gg = bx * 4 + wv;
            const int e  = c0 + 2 * lane;
            float pmA[2], pzA[2], paA[2];
            #pragma unroll
            for (int c = 0; c < 2; ++c) {
                float s0 = acc[0][c], s1 = acc[1][c], s2 = acc[2][c], s3 = acc[3][c];
                float m  = fmaxf(fmaxf(s0, s1), fmaxf(s2, s3));
                float p0 = __expf(s0 - m), p1 = __expf(s1 - m);
                float p2 = __expf(s2 - m), p3 = __expf(s3 - m);
                const int ee = e + c;
                float a = p0 * As[rw + 0][ee] + p1 * As[rw + 1][ee]
                        + p2 * As[rw + 2][ee] + p3 * As[rw + 3][ee];
                pmA[c] = m; pzA[c] = p0 + p1 + p2 + p3; paA[c] = a;
            }
            *(float2*)(pm + (size_t)gg * 256 + e) = make_float2(pmA[0], pmA[1]);
            *(float2*)(pz + (size_t)gg * 256 + e) = make_float2(pzA[0], pzA[1]);
            *(float2*)(pa + (size_t)gg * 256 + e) = make_float2(paA[0], paA[1]);
        } else {
            const int e = c0 - 256 + 2 * lane;
            #pragma unroll
            for (int r = 0; r < 4; ++r)
                *(float2*)(gout + (size_t)(r0 + rw + r) * 256 + e) =
                    make_float2(acc[r][0], acc[r][1]);
        }
    }
}

template<int MODE>
__global__ __launch_bounds__(256) void fb_ck(
    const float* __restrict__ pm, const float* __restrict__ pz,
    const float* __restrict__ pa,
    const float* __restrict__ u2t, const float* __restrict__ updb,
    const float* __restrict__ awt,
    const float* __restrict__ g2, float* __restrict__ outp)
{
    const int b = blockIdx.x, e = threadIdx.x;
    float m = -1e30f, z = 0.f, a = 0.f;
    #pragma unroll 4
    for (int g = 0; g < 32; ++g) {
        size_t idx = (size_t)(b * 32 + g) * 256 + e;
        float mq = pm[idx], zq = pz[idx], aq = pa[idx];
        float mn = fmaxf(m, mq);
        float sA = __expf(m - mn), sB = __expf(mq - mn);
        z = z * sA + zq * sB;
        a = a * sA + aq * sB;
        m = mn;
    }
    __shared__ float aggs[256];
    __shared__ float cs[256];
    aggs[e] = 1.f / (1.f + __expf(-(a / z)));
    __syncthreads();
    float c = updb[e];
    #pragma unroll 8
    for (int d = 0; d < 256; ++d)
        c = fmaf(aggs[d], u2t[d * 256 + e], c);
    if (MODE == 0) {
        cs[e] = c;
        __syncthreads();
        float ca = 0.f;
        #pragma unroll 8
        for (int d = 0; d < 256; ++d)
            ca = fmaf(cs[d], awt[d * 256 + e], ca);
        outp[b * 256 + e] = ca;
    } else {
        const int r0 = b * 128 + blockIdx.y * 16;
        #pragma unroll 4
        for (int r = 0; r < 16; ++r) {
            size_t off = (size_t)(r0 + r) * 256 + e;
            outp[off] = g2[off] + c;
        }
    }
}

// ---------------------------------------------------------------------------
extern "C" void kernel_launch(void* const* d_in, const int* in_sizes, int n_in,
                              void* d_out, int out_size, void* d_ws, size_t ws_size,
                              hipStream_t stream) {
    KArgs ka;
    ka.feat   = (const float*)d_in[0];
    ka.mask   = (const float*)d_in[1];
    ka.agg_w  = (const float*)d_in[2];
    ka.agg_b  = (const float*)d_in[3];
    ka.attn_w = (const float*)d_in[4];   // attn_b (d_in[5]) and W2 cancel in softmax
    ka.upd_w  = (const float*)d_in[6];
    ka.upd_b  = (const float*)d_in[7];
    ka.out    = (float*)d_out;

    float* p = (float*)d_ws;
    ka.wt12 = p; p += 256 * 512;
    ka.u1t  = p; p += 256 * 256;
    ka.awt  = p; p += 256 * 256;
    ka.u2t  = p; p += 256 * 256;
    ka.buf0 = p; p += 2048 * 256;
    ka.buf1 = p; p += 2048 * 256;
    ka.pz   = p; p += 512 * 256;
    ka.pa   = p; p += 512 * 256;
    ka.cAv  = p; p += 16 * 256;
    float* wt3 = p; p += 256 * 512;   // fallback-only
    float* pm  = p; p += 512 * 256;   // fallback-only

    void* params[] = { (void*)&ka };
    hipError_t err = hipLaunchCooperativeKernel(
        reinterpret_cast<const void*>(mega), dim3(NBLK), dim3(NTHR), params, 0, stream);

    if (err != hipSuccess) {
        // -------- proven multi-launch fallback (R2 structure) --------
        fb_prep<<<80, 256, 0, stream>>>(ka.agg_w, ka.attn_w, ka.upd_w,
                                        ka.wt12, wt3, ka.awt, ka.u2t);
        fb_gemm<1, 0><<<dim3(128, 2), 256, 0, stream>>>(
            ka.feat, ka.awt, 256, ka.mask, nullptr, ka.agg_b, ka.buf0,
            nullptr, nullptr, nullptr);
        fb_gemm<0, 1><<<dim3(128, 4), 256, 0, stream>>>(
            ka.buf0, ka.wt12, 512, nullptr, nullptr, nullptr, ka.buf1, pm, ka.pz, ka.pa);
        fb_ck<0><<<16, 256, 0, stream>>>(pm, ka.pz, ka.pa, ka.u2t, ka.upd_b, ka.awt,
                                         nullptr, ka.cAv);
        fb_gemm<2, 1><<<dim3(128, 4), 256, 0, stream>>>(
            ka.buf1, ka.wt12, 512, ka.mask, ka.cAv, ka.agg_b, ka.buf0, pm, ka.pz, ka.pa);
        fb_ck<0><<<16, 256, 0, stream>>>(pm, ka.pz, ka.pa, ka.u2t, ka.upd_b, ka.awt,
                                         nullptr, ka.cAv);
        fb_gemm<2, 1><<<dim3(128, 4), 256, 0, stream>>>(
            ka.buf0, wt3, 512, ka.mask, ka.cAv, ka.agg_b, ka.buf1, pm, ka.pz, ka.pa);
        fb_ck<1><<<dim3(16, 8), 256, 0, stream>>>(pm, ka.pz, ka.pa, ka.u2t, ka.upd_b,
                                                  ka.awt, ka.buf1, ka.out);
    }
}